// Round 8
// baseline (234.348 us; speedup 1.0000x reference)
//
#include <hip/hip_runtime.h>
#include <stdint.h>

// Problem constants
#define NMOL 4096
#define NATOMS (NMOL * 64)     // 262144
#define NF 124
#define NT 8
#define ROWV 125               // x_padded row stride in floats
#define CAP 65536              // list slots per type (worst case all atoms one type)

// ws layout (bytes)
#define WS_DCONST  0           // float[8]   (= T - c_t + b3_t)
#define WS_CURSOR  64          // uint[8]    (preset to t*CAP; post-sort = t*CAP + count_t)
#define WS_W1G     128         // ushort[8*1024*8] bf16, B-frag order    (128 KB)
#define WS_W2T     131200      // ushort[8*16*64]  bf16, [t][g][h]       (16 KB)
#define WS_LIST    147712      // uint[NT*CAP]                           (2 MB)

#define HS 72                  // h1 row stride in shorts

typedef __attribute__((ext_vector_type(8))) short short8;
typedef __attribute__((ext_vector_type(4))) float floatx4;
typedef __attribute__((ext_vector_type(4), aligned(4))) float floatx4u;  // 4B-aligned vec load
typedef __attribute__((ext_vector_type(4))) unsigned int uint4v;

__device__ __forceinline__ unsigned short f2bf(float f) {
    unsigned u = __builtin_bit_cast(unsigned, f);
    u += 0x7fffu + ((u >> 16) & 1u);
    return (unsigned short)(u >> 16);
}
__device__ __forceinline__ unsigned pk2(float a, float b) {
    return (unsigned)f2bf(a) | ((unsigned)f2bf(b) << 16);
}

// ---------------- K1: setup (constants + cursors + weight prep + out-zero) ----------------
// b==0: dconst fp32 + cursor[t]=t*CAP; b 1..8: W1G/W2T for type b-1; b 9..24: zero out
__global__ __launch_bounds__(256) void k_setup(const float* __restrict__ W1,
                                               const float* __restrict__ b1,
                                               const float* __restrict__ W2,
                                               const float* __restrict__ b2,
                                               const float* __restrict__ W3,
                                               const float* __restrict__ b3,
                                               float* __restrict__ dconst,
                                               unsigned* __restrict__ cursor,
                                               unsigned short* __restrict__ W1G,
                                               unsigned short* __restrict__ W2T,
                                               float* __restrict__ out) {
    int tid = threadIdx.x, b = blockIdx.x;
    if (b == 0) {
        __shared__ float c[NT];
        if (tid < 128) {           // exact fp32 constant c_t = MLP_t(0)
            int t = tid >> 4, g = tid & 15;
            float acc = b2[t * 16 + g];
            for (int h = 0; h < 64; ++h) {
                float h1 = b1[t * 64 + h];
                h1 = h1 > 0.f ? h1 : 0.f;
                acc += h1 * W2[(size_t)t * 1024 + h * 16 + g];
            }
            float h2 = acc > 0.f ? acc : 0.f;
            float v = h2 * W3[t * 16 + g];
            #pragma unroll
            for (int off = 1; off < 16; off <<= 1) v += __shfl_xor(v, off);
            if (g == 0) c[t] = v + b3[t];
        }
        if (tid < NT) cursor[tid] = (unsigned)(tid * CAP);
        __syncthreads();
        if (tid == 0) {
            float T_ = 0.f;
            for (int i = 0; i < NT; ++i) T_ += c[i];
            for (int i = 0; i < NT; ++i) dconst[i] = T_ - c[i] + b3[i];
        }
    } else if (b <= 8) {
        int t = b - 1;
        // W1 -> W1G: B-fragment order. chunk id = ks*256 + quad*64 + n*16 + l15,
        // holds bf16 of W1[k = ks*32+quad*8+j][h = n*16+l15], j=0..7 (k>=124 -> 0)
        const float* w1g = W1 + (size_t)t * NF * 64;
        unsigned short* dst = W1G + (size_t)t * 8192;
        for (int id = tid; id < 1024; id += 256) {
            int l15 = id & 15, n = (id >> 4) & 3, quad = (id >> 6) & 3, ks = id >> 8;
            int h = n * 16 + l15;
            int k0 = ks * 32 + quad * 8;
            unsigned u[4];
            #pragma unroll
            for (int j = 0; j < 4; ++j) {
                int ka = k0 + 2 * j, kb = k0 + 2 * j + 1;
                unsigned short lo = (ka < NF) ? f2bf(w1g[ka * 64 + h]) : (unsigned short)0;
                unsigned short hi = (kb < NF) ? f2bf(w1g[kb * 64 + h]) : (unsigned short)0;
                u[j] = (unsigned)lo | ((unsigned)hi << 16);
            }
            *(uint4v*)(dst + id * 8) = (uint4v){u[0], u[1], u[2], u[3]};
        }
        // W2 -> W2T: [t][g][h]
        unsigned short* d2 = W2T + (size_t)t * 1024;
        for (int i = tid; i < 1024; i += 256) {
            int g = i >> 6, h = i & 63;
            d2[i] = f2bf(W2[(size_t)t * 1024 + h * 16 + g]);
        }
    } else {
        out[(b - 9) * 256 + tid] = 0.0f;
    }
}

// ---------------- K2: one-pass type sort into fixed segments ----------------
__global__ __launch_bounds__(256) void k_sort(const float* __restrict__ x,
                                              const float* __restrict__ mask,
                                              unsigned* __restrict__ cursor,
                                              unsigned* __restrict__ list) {
    __shared__ unsigned hist[NT], basep[NT], cur[NT];
    int tid = threadIdx.x;
    if (tid < NT) { hist[tid] = 0u; cur[tid] = 0u; }
    __syncthreads();
    int base = blockIdx.x * 1024;
    unsigned char tb[4];
    for (int i = 0; i < 4; ++i) {
        int atom = base + i * 256 + tid;
        float tf = x[(size_t)atom * ROWV];
        float m  = mask[atom];
        tb[i] = 0xFF;
        if (m != 0.0f) { tb[i] = (unsigned char)(int)tf; atomicAdd(&hist[tb[i]], 1u); }
    }
    __syncthreads();
    if (tid < NT && hist[tid]) basep[tid] = atomicAdd(&cursor[tid], hist[tid]);
    __syncthreads();
    for (int i = 0; i < 4; ++i) {
        if (tb[i] != 0xFF) {
            unsigned p = basep[tb[i]] + atomicAdd(&cur[tb[i]], 1u);
            list[p] = (unsigned)(base + i * 256 + tid);
        }
    }
}

// ---------------- K3: MLP over type-sorted atoms; barrier-free, 18.4 KB LDS ----------------
__global__ __launch_bounds__(256, 6) void k_mlp(const float* __restrict__ x,
                                                const unsigned short* __restrict__ W1G,
                                                const float* __restrict__ b1,
                                                const unsigned short* __restrict__ W2T,
                                                const float* __restrict__ b2,
                                                const float* __restrict__ W3,
                                                const unsigned* __restrict__ cursor,
                                                const float* __restrict__ dconst,
                                                const unsigned* __restrict__ list,
                                                float* __restrict__ out) {
    __shared__ unsigned short sH[128 * HS];   // h1 bf16 (18 KB), per-wave rows only

    int t    = blockIdx.x >> 9;               // 512 tiles per type segment
    int tile = blockIdx.x & 511;
    int cnt  = (int)(cursor[t] - (unsigned)(t * CAP));
    int valid = cnt - (tile << 7);
    if (valid <= 0) return;
    if (valid > 128) valid = 128;
    int rowstart = t * CAP + (tile << 7);

    int tid  = threadIdx.x;
    int wv   = tid >> 6;
    int lane = tid & 63;
    int quad = lane >> 4, l15 = lane & 15;
    int rowbase = wv * 32;

    // ---- row ids: lanes 0..31 hold this wave's 32 rows (clamped), shfl-distributed ----
    unsigned myid = 0;
    if (lane < 32) {
        int row = rowbase + lane;
        myid = list[rowstart + (row < valid ? row : 0)];
    }

    float b1v[4];
    #pragma unroll
    for (int n = 0; n < 4; ++n) b1v[n] = b1[t * 64 + n * 16 + l15];

    // ---- A-fragments: gather rows straight into regs, bf16 once ----
    short8 afrag[2][4];
    #pragma unroll
    for (int m = 0; m < 2; ++m) {
        unsigned atom = (unsigned)__shfl((int)myid, m * 16 + l15);
        const float* rp = x + (size_t)atom * ROWV + 1;
        #pragma unroll
        for (int ks = 0; ks < 4; ++ks) {
            int k0 = ks * 32 + quad * 8;
            floatx4 f0 = (floatx4)(*(const floatx4u*)(rp + k0));
            floatx4 f1 = (floatx4)0.f;
            if (!(ks == 3 && quad == 3))         // k>=124: OOB guard; W1G pad is zero
                f1 = (floatx4)(*(const floatx4u*)(rp + k0 + 4));
            uint4v uu = (uint4v){pk2(f0[0], f0[1]), pk2(f0[2], f0[3]),
                                 pk2(f1[0], f1[1]), pk2(f1[2], f1[3])};
            afrag[m][ks] = __builtin_bit_cast(short8, uu);
        }
    }

    // ---- layer 1: [32x128] x [128x64], B-frags coalesced from L2-hot W1G ----
    const unsigned short* w1t = W1G + (size_t)t * 8192;
    floatx4 c1[2][4];
    #pragma unroll
    for (int m = 0; m < 2; ++m)
        #pragma unroll
        for (int n = 0; n < 4; ++n) c1[m][n] = (floatx4)0.f;

    #pragma unroll
    for (int ks = 0; ks < 4; ++ks) {
        short8 bf[4];
        #pragma unroll
        for (int n = 0; n < 4; ++n)
            bf[n] = *(const short8*)(w1t + (size_t)(ks * 256 + quad * 64 + n * 16 + l15) * 8);
        #pragma unroll
        for (int n = 0; n < 4; ++n) {
            c1[0][n] = __builtin_amdgcn_mfma_f32_16x16x32_bf16(afrag[0][ks], bf[n], c1[0][n], 0, 0, 0);
            c1[1][n] = __builtin_amdgcn_mfma_f32_16x16x32_bf16(afrag[1][ks], bf[n], c1[1][n], 0, 0, 0);
        }
    }

    // ---- h1 = relu(c1+b1) -> sH (own-wave rows; in-order DS, no barrier) ----
    #pragma unroll
    for (int m = 0; m < 2; ++m)
        #pragma unroll
        for (int n = 0; n < 4; ++n) {
            int col = n * 16 + l15;
            #pragma unroll
            for (int r = 0; r < 4; ++r) {
                float v = c1[m][n][r] + b1v[n];
                v = v > 0.f ? v : 0.f;
                sH[(rowbase + m * 16 + quad * 4 + r) * HS + col] = f2bf(v);
            }
        }

    // ---- layer 2: [32x64] x [64x16] ----
    const unsigned short* w2t = W2T + (size_t)t * 1024;
    floatx4 c2[2];
    c2[0] = (floatx4)0.f; c2[1] = (floatx4)0.f;
    #pragma unroll
    for (int ks = 0; ks < 2; ++ks) {
        int ko = ks * 32 + quad * 8;
        short8 a0 = *(const short8*)(sH + (rowbase + l15) * HS + ko);
        short8 a1 = *(const short8*)(sH + (rowbase + 16 + l15) * HS + ko);
        short8 bw = *(const short8*)(w2t + l15 * 64 + ko);
        c2[0] = __builtin_amdgcn_mfma_f32_16x16x32_bf16(a0, bw, c2[0], 0, 0, 0);
        c2[1] = __builtin_amdgcn_mfma_f32_16x16x32_bf16(a1, bw, c2[1], 0, 0, 0);
    }

    // ---- layer 3 + constant + atomic accumulate ----
    float b2v = b2[t * 16 + l15];
    float w3v = W3[t * 16 + l15];
    float dct = dconst[t];   // includes b3
    unsigned ratom[2][4];
    #pragma unroll
    for (int m = 0; m < 2; ++m)
        #pragma unroll
        for (int r = 0; r < 4; ++r)       // all lanes active for shfl
            ratom[m][r] = (unsigned)__shfl((int)myid, m * 16 + quad * 4 + r);
    #pragma unroll
    for (int m = 0; m < 2; ++m) {
        float h2v[4];
        #pragma unroll
        for (int r = 0; r < 4; ++r) {
            float v = c2[m][r] + b2v;
            v = v > 0.f ? v : 0.f;
            h2v[r] = v * w3v;
        }
        #pragma unroll
        for (int off = 1; off < 16; off <<= 1)
            #pragma unroll
            for (int r = 0; r < 4; ++r) h2v[r] += __shfl_xor(h2v[r], off);
        if (l15 == 0) {
            #pragma unroll
            for (int r = 0; r < 4; ++r) {
                int row = rowbase + m * 16 + quad * 4 + r;
                if (row < valid)
                    atomicAdd(&out[ratom[m][r] >> 6], h2v[r] + dct);
            }
        }
    }
}

extern "C" void kernel_launch(void* const* d_in, const int* in_sizes, int n_in,
                              void* d_out, int out_size, void* d_ws, size_t ws_size,
                              hipStream_t stream) {
    const float* x    = (const float*)d_in[0];
    const float* mask = (const float*)d_in[1];
    const float* W1   = (const float*)d_in[2];
    const float* b1   = (const float*)d_in[3];
    const float* W2   = (const float*)d_in[4];
    const float* b2   = (const float*)d_in[5];
    const float* W3   = (const float*)d_in[6];
    const float* b3   = (const float*)d_in[7];
    float* out = (float*)d_out;

    char* ws = (char*)d_ws;
    float*          dconst = (float*)(ws + WS_DCONST);
    unsigned*       cursor = (unsigned*)(ws + WS_CURSOR);
    unsigned short* W1G    = (unsigned short*)(ws + WS_W1G);
    unsigned short* W2T    = (unsigned short*)(ws + WS_W2T);
    unsigned*       list   = (unsigned*)(ws + WS_LIST);

    k_setup<<<25, 256, 0, stream>>>(W1, b1, W2, b2, W3, b3, dconst, cursor, W1G, W2T, out);
    k_sort<<<256, 256, 0, stream>>>(x, mask, cursor, list);
    k_mlp<<<NT * (CAP / 128), 256, 0, stream>>>(x, W1G, b1, W2T, b2, W3,
                                                cursor, dconst, list, out);
}